// Round 1
// 434.140 us; speedup vs baseline: 1.1272x; 1.1272x over previous
//
#include <hip/hip_runtime.h>
#include <hip/hip_bf16.h>
#include <stdint.h>

// ---------------------------------------------------------------------------
// GCN forward on MI355X.
//   CSR build via 196-bucket counting sort (bucket = col>>9, 512 nodes each).
//     k_bhist   : chunked edge scan, LDS hist, writes cntmat[b][g] (b-major)
//     k_colscan : per-bucket exclusive scan of cntmat column over g
//     k_bscan   : exclusive scan of bucket totals -> bbase
//     k_bscatter: single-pass scatter, base[b]=bbase[b]+cntmat[b][g] in LDS
//                 (doubles as cursor), packed payload (row<<9 | col&511)
//     k_bcount  : grid (bucket,4): sub-block s scans its slice QUARTER into a
//                 512-counter LDS hist -> qcnt[s][node]  (slice read once)
//     k_rowptr  : per-bucket: deg = sum_s qcnt, dis = rsqrt(deg+1),
//                 rowptr = bbase[b] + in-bucket exclusive scan (buckets are
//                 node-contiguous, so no global N-scan needed)
//     k_bfill   : grid (bucket,4): cursors = rowptr + prefix(qcnt), scan own
//                 quarter, CSR fill into L2-resident window
//   Layers (agg commutes with dense: A(XW)=(AX)W; all gathers width 16; the
//   16->32->16 chain and the classifier are fused into agg epilogues via
//   16-lane shuffle broadcasts -- h2 is never materialized):
//     t1  = (x @ W1) * dis                        (wave-per-row, W1 in regs)
//     hs1 = relu(dis*gather(t1) + b1) * dis       (k_agg_rb)
//     t3  = (relu((dis*gather(hs1))@W2+b2)@W3)*dis (k_agg_mid, fused)
//     h   = relu(dis*gather(t3) + b3) -> outh
//     out = h @ Wc + bc               -> outc      (k_agg_out, fused)
//   gather16 is 16-edge unrolled with 4 independent accumulators: the agg
//   kernels are latency-bound on random 64B row gathers; 16 independent
//   row-loads per wave iteration keep ~16 lines in flight (was ~4).
//   No fp atomics anywhere.
// ---------------------------------------------------------------------------

__device__ __forceinline__ int blockScanExclusive256(int v, int* wsum) {
  int lane = threadIdx.x & 63;
  int wid  = threadIdx.x >> 6;
  int inc = v;
#pragma unroll
  for (int d = 1; d < 64; d <<= 1) {
    int y = __shfl_up(inc, d, 64);
    if (lane >= d) inc += y;
  }
  if (lane == 63) wsum[wid] = inc;
  __syncthreads();
  if (threadIdx.x == 0) {
    int s = 0;
#pragma unroll
    for (int w = 0; w < 4; ++w) { int t = wsum[w]; wsum[w] = s; s += t; }
  }
  __syncthreads();
  return inc - v + wsum[wid];
}

// ---- per-block bucket histogram -> cntmat[b*G + g] (bucket-major) ----
__global__ __launch_bounds__(256) void k_bhist(const int* __restrict__ ecol,
                                               int* __restrict__ cntmat,
                                               int e, int chunk, int nb) {
  __shared__ int h[256];
  h[threadIdx.x] = 0;
  __syncthreads();
  int g = blockIdx.x, G = gridDim.x;
  int s0 = g * chunk;
  int s1 = min(e, s0 + chunk);
  int i = s0 + threadIdx.x;
  for (; i + 768 < s1; i += 1024) {
    int c0 = ecol[i], c1 = ecol[i + 256], c2 = ecol[i + 512], c3 = ecol[i + 768];
    atomicAdd(&h[c0 >> 9], 1);
    atomicAdd(&h[c1 >> 9], 1);
    atomicAdd(&h[c2 >> 9], 1);
    atomicAdd(&h[c3 >> 9], 1);
  }
  for (; i < s1; i += 256) atomicAdd(&h[ecol[i] >> 9], 1);
  __syncthreads();
  for (int b = threadIdx.x; b < nb; b += 256) cntmat[b * G + g] = h[b];
}

// ---- per-bucket column scan over g; column total -> colsum[b] ----
__global__ __launch_bounds__(256) void k_colscan(int* __restrict__ cntmat,
                                                 int* __restrict__ colsum, int G) {
  __shared__ int wsum[4];
  __shared__ int carry_s;
  int b = blockIdx.x;
  if (threadIdx.x == 0) carry_s = 0;
  __syncthreads();
  for (int base = 0; base < G; base += 256) {
    int i = base + threadIdx.x;
    int v = (i < G) ? cntmat[b * G + i] : 0;
    int ex = blockScanExclusive256(v, wsum);
    int c = carry_s;
    __syncthreads();
    if (i < G) cntmat[b * G + i] = ex + c;
    if (threadIdx.x == 255) carry_s = c + ex + v;
    __syncthreads();
  }
  if (threadIdx.x == 0) colsum[b] = carry_s;
}

// ---- bucket exclusive scan (1 block) ----
__global__ __launch_bounds__(256) void k_bscan(const int* __restrict__ colsum,
                                               int* __restrict__ bbase,
                                               int nb, int etot) {
  __shared__ int wsum[4];
  __shared__ int carry_s;
  if (threadIdx.x == 0) carry_s = 0;
  __syncthreads();
  for (int base = 0; base < nb; base += 256) {
    int i = base + threadIdx.x;
    int v = (i < nb) ? colsum[i] : 0;
    int ex = blockScanExclusive256(v, wsum);
    int c = carry_s;
    __syncthreads();
    if (i < nb) bbase[i] = ex + c;
    if (threadIdx.x == 255) carry_s = c + ex + v;
    __syncthreads();
  }
  if (threadIdx.x == 0) bbase[nb] = etot;
}

// ---- single-pass counting-sort scatter ----
__global__ __launch_bounds__(256) void k_bscatter(const int* __restrict__ erow,
                                                  const int* __restrict__ ecol,
                                                  const int* __restrict__ cntmat,
                                                  const int* __restrict__ bbase,
                                                  unsigned* __restrict__ sorted,
                                                  int e, int chunk, int nb) {
  __shared__ int base[256];
  int g = blockIdx.x, G = gridDim.x;
  for (int b = threadIdx.x; b < nb; b += 256)
    base[b] = bbase[b] + cntmat[b * G + g];
  __syncthreads();
  int s0 = g * chunk;
  int s1 = min(e, s0 + chunk);
  int i = s0 + threadIdx.x;
  for (; i + 768 < s1; i += 1024) {
    int c0 = ecol[i],       c1 = ecol[i + 256], c2 = ecol[i + 512], c3 = ecol[i + 768];
    int r0 = erow[i],       r1 = erow[i + 256], r2 = erow[i + 512], r3 = erow[i + 768];
    int p0 = atomicAdd(&base[c0 >> 9], 1);
    int p1 = atomicAdd(&base[c1 >> 9], 1);
    int p2 = atomicAdd(&base[c2 >> 9], 1);
    int p3 = atomicAdd(&base[c3 >> 9], 1);
    sorted[p0] = ((unsigned)r0 << 9) | (unsigned)(c0 & 511);
    sorted[p1] = ((unsigned)r1 << 9) | (unsigned)(c1 & 511);
    sorted[p2] = ((unsigned)r2 << 9) | (unsigned)(c2 & 511);
    sorted[p3] = ((unsigned)r3 << 9) | (unsigned)(c3 & 511);
  }
  for (; i < s1; i += 256) {
    int c = ecol[i];
    int p = atomicAdd(&base[c >> 9], 1);
    sorted[p] = ((unsigned)erow[i] << 9) | (unsigned)(c & 511);
  }
}

// ---- degree count: grid (bucket,4); sub-block s scans its slice QUARTER
//      into 512-counter LDS hist -> qcnt[s*stride + node] ----
__global__ __launch_bounds__(256) void k_bcount(const unsigned* __restrict__ sorted,
                                                const int* __restrict__ bbase,
                                                int* __restrict__ qcnt,
                                                int n) {
  __shared__ int h[512];
  int b = blockIdx.x, s = blockIdx.y;
  h[threadIdx.x] = 0; h[threadIdx.x + 256] = 0;
  __syncthreads();
  int s0 = bbase[b], s1 = bbase[b + 1];
  int q = ((s1 - s0) + 3) >> 2;
  int q0 = s0 + s * q, q1 = min(s1, q0 + q);
#pragma unroll 4
  for (int i = q0 + threadIdx.x; i < q1; i += 256)
    atomicAdd(&h[sorted[i] & 511], 1);
  __syncthreads();
  int nodebase = b << 9;
  for (int j = threadIdx.x; j < 512; j += 256) {
    int node = nodebase + j;
    if (node < n) qcnt[s * n + node] = h[j];
  }
}

// ---- per-bucket rowptr + dis: deg = sum_s qcnt; dis = rsqrt(deg+1);
//      rowptr = bbase[b] + in-bucket exclusive prefix of deg.
//      (buckets are node-contiguous, so the global N-scan is unnecessary) ----
__global__ __launch_bounds__(256) void k_rowptr(const int* __restrict__ qcnt,
                                                const int* __restrict__ bbase,
                                                float* __restrict__ dis,
                                                int* __restrict__ rowptr,
                                                int n, int etot) {
  __shared__ int wsum[4];
  int b = blockIdx.x;
  int nodebase = b << 9;
  int n0 = nodebase + 2 * threadIdx.x;
  int n1 = n0 + 1;
  int d0 = 0, d1 = 0;
  if (n0 < n) d0 = qcnt[n0] + qcnt[n + n0] + qcnt[2 * n + n0] + qcnt[3 * n + n0];
  if (n1 < n) d1 = qcnt[n1] + qcnt[n + n1] + qcnt[2 * n + n1] + qcnt[3 * n + n1];
  if (n0 < n) dis[n0] = rsqrtf((float)(d0 + 1));  // +1 self loop
  if (n1 < n) dis[n1] = rsqrtf((float)(d1 + 1));
  int v = d0 + d1;
  int ex = blockScanExclusive256(v, wsum);
  int base = bbase[b] + ex;
  if (n0 < n) rowptr[n0] = base;
  if (n1 < n) rowptr[n1] = base + d0;
  if (b == 0 && threadIdx.x == 0) rowptr[n] = etot;
}

// ---- CSR fill: grid (bucket,4); cursors = rowptr + prefix(qcnt); each
//      sub-block scans only its slice quarter ----
__global__ __launch_bounds__(256) void k_bfill(const unsigned* __restrict__ sorted,
                                               const int* __restrict__ bbase,
                                               const int* __restrict__ rowptr,
                                               const int* __restrict__ qcnt,
                                               int* __restrict__ csr, int n) {
  __shared__ int cur[512];
  int b = blockIdx.x, s = blockIdx.y;
  int nodebase = b << 9;
  for (int j = threadIdx.x; j < 512; j += 256) {
    int node = nodebase + j;
    if (node < n) {
      int c = rowptr[node];
      for (int t = 0; t < s; ++t) c += qcnt[t * n + node];
      cur[j] = c;
    }
  }
  __syncthreads();
  int s0 = bbase[b], s1 = bbase[b + 1];
  int q = ((s1 - s0) + 3) >> 2;
  int q0 = s0 + s * q, q1 = min(s1, q0 + q);
#pragma unroll 4
  for (int i = q0 + threadIdx.x; i < q1; i += 256) {
    unsigned v = sorted[i];
    int pos = atomicAdd(&cur[v & 511], 1);
    csr[pos] = (int)(v >> 9);
  }
}

// ---- layer-1 transform: wave per row, W1 (512x16) held in registers ----
__global__ __launch_bounds__(256) void k_transform1(
    const float* __restrict__ x, const float* __restrict__ W,
    const float* __restrict__ dis, float* __restrict__ hs, int n) {
  int L = threadIdx.x & 63;
  int wid = blockIdx.x * 4 + (threadIdx.x >> 6);
  int nw = gridDim.x * 4;

  float w[8][16];
  const float4* W4 = reinterpret_cast<const float4*>(W);
#pragma unroll
  for (int i = 0; i < 4; ++i) {
#pragma unroll
    for (int c4 = 0; c4 < 4; ++c4) {
      float4 va = W4[(4 * L + i) * 4 + c4];
      w[i][c4 * 4 + 0] = va.x; w[i][c4 * 4 + 1] = va.y;
      w[i][c4 * 4 + 2] = va.z; w[i][c4 * 4 + 3] = va.w;
      float4 vb = W4[(256 + 4 * L + i) * 4 + c4];
      w[4 + i][c4 * 4 + 0] = vb.x; w[4 + i][c4 * 4 + 1] = vb.y;
      w[4 + i][c4 * 4 + 2] = vb.z; w[4 + i][c4 * 4 + 3] = vb.w;
    }
  }
  int col = ((L & 1) << 3) | ((L & 2) << 1) | ((L & 4) >> 1) | ((L & 8) >> 3);

  for (int r = wid; r < n; r += nw) {
    const float4* xr = reinterpret_cast<const float4*>(x + (size_t)r * 512);
    float4 v0 = xr[L];
    float4 v1 = xr[64 + L];
    float acc[16];
#pragma unroll
    for (int c = 0; c < 16; ++c) {
      float a = v0.x * w[0][c];
      a = fmaf(v0.y, w[1][c], a);
      a = fmaf(v0.z, w[2][c], a);
      a = fmaf(v0.w, w[3][c], a);
      a = fmaf(v1.x, w[4][c], a);
      a = fmaf(v1.y, w[5][c], a);
      a = fmaf(v1.z, w[6][c], a);
      a = fmaf(v1.w, w[7][c], a);
      acc[c] = a;
    }
#pragma unroll
    for (int j = 0; j < 8; ++j) {
      float send = (L & 1) ? acc[j] : acc[j + 8];
      float recv = __shfl_xor(send, 1, 64);
      acc[j] = ((L & 1) ? acc[j + 8] : acc[j]) + recv;
    }
#pragma unroll
    for (int j = 0; j < 4; ++j) {
      float send = (L & 2) ? acc[j] : acc[j + 4];
      float recv = __shfl_xor(send, 2, 64);
      acc[j] = ((L & 2) ? acc[j + 4] : acc[j]) + recv;
    }
#pragma unroll
    for (int j = 0; j < 2; ++j) {
      float send = (L & 4) ? acc[j] : acc[j + 2];
      float recv = __shfl_xor(send, 4, 64);
      acc[j] = ((L & 4) ? acc[j + 2] : acc[j]) + recv;
    }
    {
      float send = (L & 8) ? acc[0] : acc[1];
      float recv = __shfl_xor(send, 8, 64);
      acc[0] = ((L & 8) ? acc[1] : acc[0]) + recv;
    }
    float s = acc[0];
    s += __shfl_xor(s, 16, 64);
    s += __shfl_xor(s, 32, 64);
    if (L < 16) hs[(size_t)r * 16 + col] = s * dis[r];
  }
}

// ---- common gather: acc = self + sum of neighbor rows.
//      16-edge unroll, 4 independent accumulators: 16 independent 64B row
//      loads in flight per wave iteration (latency-bound pattern; MLP is
//      the limiter, not cache bandwidth). int indexing keeps addressing in
//      the 32-bit-voffset form and VGPR use low. ----
__device__ __forceinline__ float gather16(const float* __restrict__ hs,
                                          const int* __restrict__ rowptr,
                                          const int* __restrict__ csr,
                                          int node, int f) {
  float acc0 = hs[(node << 4) + f];  // self loop (hs already *dis)
  int e0 = rowptr[node], e1 = rowptr[node + 1];
  int e = e0;
  float acc1 = 0.f, acc2 = 0.f, acc3 = 0.f;
  for (; e + 16 <= e1; e += 16) {
    int r0  = csr[e + 0],  r1  = csr[e + 1],  r2  = csr[e + 2],  r3  = csr[e + 3];
    int r4  = csr[e + 4],  r5  = csr[e + 5],  r6  = csr[e + 6],  r7  = csr[e + 7];
    int r8  = csr[e + 8],  r9  = csr[e + 9],  r10 = csr[e + 10], r11 = csr[e + 11];
    int r12 = csr[e + 12], r13 = csr[e + 13], r14 = csr[e + 14], r15 = csr[e + 15];
    float v0  = hs[(r0  << 4) + f], v1  = hs[(r1  << 4) + f];
    float v2  = hs[(r2  << 4) + f], v3  = hs[(r3  << 4) + f];
    float v4  = hs[(r4  << 4) + f], v5  = hs[(r5  << 4) + f];
    float v6  = hs[(r6  << 4) + f], v7  = hs[(r7  << 4) + f];
    float v8  = hs[(r8  << 4) + f], v9  = hs[(r9  << 4) + f];
    float v10 = hs[(r10 << 4) + f], v11 = hs[(r11 << 4) + f];
    float v12 = hs[(r12 << 4) + f], v13 = hs[(r13 << 4) + f];
    float v14 = hs[(r14 << 4) + f], v15 = hs[(r15 << 4) + f];
    acc0 += (v0 + v1) + (v2 + v3);
    acc1 += (v4 + v5) + (v6 + v7);
    acc2 += (v8 + v9) + (v10 + v11);
    acc3 += (v12 + v13) + (v14 + v15);
  }
  for (; e + 4 <= e1; e += 4) {
    int r0 = csr[e + 0], r1 = csr[e + 1], r2 = csr[e + 2], r3 = csr[e + 3];
    float v0 = hs[(r0 << 4) + f], v1 = hs[(r1 << 4) + f];
    float v2 = hs[(r2 << 4) + f], v3 = hs[(r3 << 4) + f];
    acc0 += (v0 + v1) + (v2 + v3);
  }
  for (; e < e1; ++e) acc0 += hs[(csr[e] << 4) + f];
  return (acc0 + acc1) + (acc2 + acc3);
}

// out = relu(dis*acc + b) * dis   (layer-1 agg, prescaled for next gather)
__global__ __launch_bounds__(256) void k_agg_rb(
    const float* __restrict__ hs, const int* __restrict__ rowptr,
    const int* __restrict__ csr, const float* __restrict__ dis,
    const float* __restrict__ b, float* __restrict__ out, int n) {
  int node = blockIdx.x * 16 + threadIdx.x / 16;
  int f = threadIdx.x % 16;
  if (node >= n) return;
  float acc = gather16(hs, rowptr, csr, node, f);
  float d = dis[node];
  float t = fmaxf(fmaf(d, acc, b[f]), 0.f);
  out[(node << 4) + f] = t * d;
}

// mid: t3 = (relu((dis*acc)@W2 + b2) @ W3) * dis   -- 16->32->16 in-register
__global__ __launch_bounds__(256) void k_agg_mid(
    const float* __restrict__ hs, const int* __restrict__ rowptr,
    const int* __restrict__ csr, const float* __restrict__ dis,
    const float* __restrict__ W2, const float* __restrict__ b2,
    const float* __restrict__ W3, float* __restrict__ out, int n) {
  __shared__ float w2s[512];  // [16][32]
  __shared__ float w3s[512];  // [32][16]
  __shared__ float b2s[32];
  for (int i = threadIdx.x; i < 512; i += 256) { w2s[i] = W2[i]; w3s[i] = W3[i]; }
  if (threadIdx.x < 32) b2s[threadIdx.x] = b2[threadIdx.x];
  __syncthreads();
  int node = blockIdx.x * 16 + threadIdx.x / 16;
  int f = threadIdx.x % 16;
  if (node >= n) return;
  float acc = gather16(hs, rowptr, csr, node, f);
  float d = dis[node];
  float v = d * acc;  // g2[f]
  int base = threadIdx.x & 48;  // 16-group base lane in wave
  float a0 = b2s[f], a1 = b2s[f + 16];
#pragma unroll
  for (int k = 0; k < 16; ++k) {
    float vk = __shfl(v, base + k, 64);
    a0 = fmaf(vk, w2s[k * 32 + f], a0);
    a1 = fmaf(vk, w2s[k * 32 + 16 + f], a1);
  }
  a0 = fmaxf(a0, 0.f);
  a1 = fmaxf(a1, 0.f);
  float t = 0.f;
#pragma unroll
  for (int c = 0; c < 16; ++c) {
    float h0 = __shfl(a0, base + c, 64);
    float h1 = __shfl(a1, base + c, 64);
    t = fmaf(h0, w3s[c * 16 + f], t);
    t = fmaf(h1, w3s[(c + 16) * 16 + f], t);
  }
  out[(node << 4) + f] = t * d;
}

// final: h = relu(dis*acc + b3) -> outh;  out = h@Wc + bc -> outc
__global__ __launch_bounds__(256) void k_agg_out(
    const float* __restrict__ hs, const int* __restrict__ rowptr,
    const int* __restrict__ csr, const float* __restrict__ dis,
    const float* __restrict__ b3, const float* __restrict__ Wc,
    const float* __restrict__ bc, float* __restrict__ outh,
    float* __restrict__ outc, int n) {
  __shared__ float wcs[256];  // [16][16]
  __shared__ float b3s[16];
  __shared__ float bcs[16];
  if (threadIdx.x < 256) wcs[threadIdx.x] = Wc[threadIdx.x];
  if (threadIdx.x < 16) { b3s[threadIdx.x] = b3[threadIdx.x]; bcs[threadIdx.x] = bc[threadIdx.x]; }
  __syncthreads();
  int node = blockIdx.x * 16 + threadIdx.x / 16;
  int f = threadIdx.x % 16;
  if (node >= n) return;
  float acc = gather16(hs, rowptr, csr, node, f);
  float d = dis[node];
  float h = fmaxf(fmaf(d, acc, b3s[f]), 0.f);
  outh[(node << 4) + f] = h;
  int base = threadIdx.x & 48;
  float o = bcs[f];
#pragma unroll
  for (int k = 0; k < 16; ++k) {
    float hk = __shfl(h, base + k, 64);
    o = fmaf(hk, wcs[k * 16 + f], o);
  }
  outc[(node << 4) + f] = o;
}

extern "C" void kernel_launch(void* const* d_in, const int* in_sizes, int n_in,
                              void* d_out, int out_size, void* d_ws, size_t ws_size,
                              hipStream_t stream) {
  (void)n_in; (void)out_size;
  const float* x  = (const float*)d_in[0];
  const int*   ei = (const int*)d_in[1];
  const float* W1 = (const float*)d_in[2];
  const float* b1 = (const float*)d_in[3];
  const float* W2 = (const float*)d_in[4];
  const float* b2 = (const float*)d_in[5];
  const float* W3 = (const float*)d_in[6];
  const float* b3 = (const float*)d_in[7];
  const float* Wc = (const float*)d_in[8];
  const float* bc = (const float*)d_in[9];

  const int F = 512;
  int N = in_sizes[0] / F;
  int E = in_sizes[1] / 2;
  const int* erow = ei;        // sources
  const int* ecol = ei + E;    // targets
  int NB = (N + 511) >> 9;     // buckets of 512 nodes (N<=131072)
  const int G = 1024;          // edge-scan grid (4 blocks/CU)
  int chunk = (E + G - 1) / G;

  auto align = [](size_t v) { return (v + 255) & ~(size_t)255; };
  char* p = (char*)d_ws;
  int*   cntmat = (int*)p;   p += align((size_t)NB * G * 4);
  int*   colsum = (int*)p;   p += align(256 * 4);
  int*   bbase  = (int*)p;   p += align(257 * 4);
  int*   qcnt   = (int*)p;   p += align((size_t)4 * N * 4);
  float* dis    = (float*)p; p += align((size_t)N * 4);
  int*   rowptr = (int*)p;   p += align(((size_t)N + 1) * 4);
  int*   csr    = (int*)p;   p += align((size_t)E * 4);
  unsigned* sorted = (unsigned*)p; p += align((size_t)E * 4);
  if ((size_t)(p - (char*)d_ws) > ws_size) return;  // fail visibly

  // bufA/bufB alias `sorted` (dead after CSR build). E*4 >= 2*N*16*4 here.
  float* bufA = (float*)sorted;
  float* bufB = (float*)sorted + (size_t)N * 16;

  float* outc = (float*)d_out;                   // [N,16] classifier out
  float* outh = (float*)d_out + (size_t)N * 16;  // [N,16] h

  // ---- CSR build ----
  k_bhist<<<G, 256, 0, stream>>>(ecol, cntmat, E, chunk, NB);
  k_colscan<<<NB, 256, 0, stream>>>(cntmat, colsum, G);
  k_bscan<<<1, 256, 0, stream>>>(colsum, bbase, NB, E);
  k_bscatter<<<G, 256, 0, stream>>>(erow, ecol, cntmat, bbase, sorted, E, chunk, NB);
  k_bcount<<<dim3(NB, 4), 256, 0, stream>>>(sorted, bbase, qcnt, N);
  k_rowptr<<<NB, 256, 0, stream>>>(qcnt, bbase, dis, rowptr, N, E);
  k_bfill<<<dim3(NB, 4), 256, 0, stream>>>(sorted, bbase, rowptr, qcnt, csr, N);

  // ---- layers ----
  // t1 = (x@W1)*dis
  k_transform1<<<2048, 256, 0, stream>>>(x, W1, dis, bufA, N);
  // hs1 = relu(dis*agg(t1)+b1)*dis
  k_agg_rb<<<(N + 15) / 16, 256, 0, stream>>>(bufA, rowptr, csr, dis, b1, bufB, N);
  // t3 = (relu((dis*agg(hs1))@W2+b2)@W3)*dis
  k_agg_mid<<<(N + 15) / 16, 256, 0, stream>>>(bufB, rowptr, csr, dis, W2, b2, W3, bufA, N);
  // h = relu(dis*agg(t3)+b3) -> outh;  out = h@Wc+bc -> outc
  k_agg_out<<<(N + 15) / 16, 256, 0, stream>>>(bufA, rowptr, csr, dis, b3, Wc, bc, outh, outc, N);
}

// Round 2
// 382.762 us; speedup vs baseline: 1.2785x; 1.1342x over previous
//
#include <hip/hip_runtime.h>
#include <hip/hip_bf16.h>
#include <hip/hip_fp16.h>
#include <stdint.h>

// ---------------------------------------------------------------------------
// GCN forward on MI355X.
//   CSR build via 196-bucket counting sort (bucket = col>>9, 512 nodes each).
//     k_bhist   : chunked edge scan, LDS hist, writes cntmat[b][g] (b-major)
//     k_colscan : per-bucket exclusive scan of cntmat column over g
//     k_bscan   : exclusive scan of bucket totals -> bbase
//     k_bscatter: single-pass scatter, base[b]=bbase[b]+cntmat[b][g] in LDS
//                 (doubles as cursor), packed payload (row<<9 | col&511)
//     k_bcount  : grid (bucket,4): sub-block s scans its slice QUARTER into a
//                 512-counter LDS hist -> qcnt[s][node]  (slice read once)
//     k_rowptr  : per-bucket: deg = sum_s qcnt, dis = rsqrt(deg+1),
//                 rowptr = bbase[b] + in-bucket exclusive scan
//     k_bfill   : grid (bucket,4): cursors = rowptr + prefix(qcnt), scan own
//                 quarter, CSR fill into L2-resident window
//   Layers (agg commutes with dense: A(XW)=(AX)W; all gathers width 16; the
//   16->32->16 chain and the classifier are fused into agg epilogues via
//   16-lane shuffle broadcasts -- h2 is never materialized):
//     t1  = (x @ W1) * dis                        (wave-per-row, W1 in regs)
//     hs1 = relu(dis*gather(t1) + b1) * dis       (k_agg_rb)
//     t3  = (relu((dis*gather(hs1))@W2+b2)@W3)*dis (k_agg_mid, fused)
//     h   = relu(dis*gather(t3) + b3) -> outh
//     out = h @ Wc + bc               -> outc      (k_agg_out, fused)
//   Gathered arrays (t1, hs1, t3) are stored FP16: 3.2MB each -> fits the
//   4MB per-XCD L2 (fp32 was 6.4MB and thrashed to L3). Random row reads are
//   32B (16 lanes x 2B), accumulation fp32. gather is 16-edge unrolled with
//   4 independent accumulators (~16 lines in flight per wave).
//   No fp atomics anywhere.
// ---------------------------------------------------------------------------

__device__ __forceinline__ int blockScanExclusive256(int v, int* wsum) {
  int lane = threadIdx.x & 63;
  int wid  = threadIdx.x >> 6;
  int inc = v;
#pragma unroll
  for (int d = 1; d < 64; d <<= 1) {
    int y = __shfl_up(inc, d, 64);
    if (lane >= d) inc += y;
  }
  if (lane == 63) wsum[wid] = inc;
  __syncthreads();
  if (threadIdx.x == 0) {
    int s = 0;
#pragma unroll
    for (int w = 0; w < 4; ++w) { int t = wsum[w]; wsum[w] = s; s += t; }
  }
  __syncthreads();
  return inc - v + wsum[wid];
}

// ---- per-block bucket histogram -> cntmat[b*G + g] (bucket-major) ----
__global__ __launch_bounds__(256) void k_bhist(const int* __restrict__ ecol,
                                               int* __restrict__ cntmat,
                                               int e, int chunk, int nb) {
  __shared__ int h[256];
  h[threadIdx.x] = 0;
  __syncthreads();
  int g = blockIdx.x, G = gridDim.x;
  int s0 = g * chunk;
  int s1 = min(e, s0 + chunk);
  int i = s0 + threadIdx.x;
  for (; i + 768 < s1; i += 1024) {
    int c0 = ecol[i], c1 = ecol[i + 256], c2 = ecol[i + 512], c3 = ecol[i + 768];
    atomicAdd(&h[c0 >> 9], 1);
    atomicAdd(&h[c1 >> 9], 1);
    atomicAdd(&h[c2 >> 9], 1);
    atomicAdd(&h[c3 >> 9], 1);
  }
  for (; i < s1; i += 256) atomicAdd(&h[ecol[i] >> 9], 1);
  __syncthreads();
  for (int b = threadIdx.x; b < nb; b += 256) cntmat[b * G + g] = h[b];
}

// ---- per-bucket column scan over g; column total -> colsum[b] ----
__global__ __launch_bounds__(256) void k_colscan(int* __restrict__ cntmat,
                                                 int* __restrict__ colsum, int G) {
  __shared__ int wsum[4];
  __shared__ int carry_s;
  int b = blockIdx.x;
  if (threadIdx.x == 0) carry_s = 0;
  __syncthreads();
  for (int base = 0; base < G; base += 256) {
    int i = base + threadIdx.x;
    int v = (i < G) ? cntmat[b * G + i] : 0;
    int ex = blockScanExclusive256(v, wsum);
    int c = carry_s;
    __syncthreads();
    if (i < G) cntmat[b * G + i] = ex + c;
    if (threadIdx.x == 255) carry_s = c + ex + v;
    __syncthreads();
  }
  if (threadIdx.x == 0) colsum[b] = carry_s;
}

// ---- bucket exclusive scan (1 block) ----
__global__ __launch_bounds__(256) void k_bscan(const int* __restrict__ colsum,
                                               int* __restrict__ bbase,
                                               int nb, int etot) {
  __shared__ int wsum[4];
  __shared__ int carry_s;
  if (threadIdx.x == 0) carry_s = 0;
  __syncthreads();
  for (int base = 0; base < nb; base += 256) {
    int i = base + threadIdx.x;
    int v = (i < nb) ? colsum[i] : 0;
    int ex = blockScanExclusive256(v, wsum);
    int c = carry_s;
    __syncthreads();
    if (i < nb) bbase[i] = ex + c;
    if (threadIdx.x == 255) carry_s = c + ex + v;
    __syncthreads();
  }
  if (threadIdx.x == 0) bbase[nb] = etot;
}

// ---- single-pass counting-sort scatter ----
__global__ __launch_bounds__(256) void k_bscatter(const int* __restrict__ erow,
                                                  const int* __restrict__ ecol,
                                                  const int* __restrict__ cntmat,
                                                  const int* __restrict__ bbase,
                                                  unsigned* __restrict__ sorted,
                                                  int e, int chunk, int nb) {
  __shared__ int base[256];
  int g = blockIdx.x, G = gridDim.x;
  for (int b = threadIdx.x; b < nb; b += 256)
    base[b] = bbase[b] + cntmat[b * G + g];
  __syncthreads();
  int s0 = g * chunk;
  int s1 = min(e, s0 + chunk);
  int i = s0 + threadIdx.x;
  for (; i + 768 < s1; i += 1024) {
    int c0 = ecol[i],       c1 = ecol[i + 256], c2 = ecol[i + 512], c3 = ecol[i + 768];
    int r0 = erow[i],       r1 = erow[i + 256], r2 = erow[i + 512], r3 = erow[i + 768];
    int p0 = atomicAdd(&base[c0 >> 9], 1);
    int p1 = atomicAdd(&base[c1 >> 9], 1);
    int p2 = atomicAdd(&base[c2 >> 9], 1);
    int p3 = atomicAdd(&base[c3 >> 9], 1);
    sorted[p0] = ((unsigned)r0 << 9) | (unsigned)(c0 & 511);
    sorted[p1] = ((unsigned)r1 << 9) | (unsigned)(c1 & 511);
    sorted[p2] = ((unsigned)r2 << 9) | (unsigned)(c2 & 511);
    sorted[p3] = ((unsigned)r3 << 9) | (unsigned)(c3 & 511);
  }
  for (; i < s1; i += 256) {
    int c = ecol[i];
    int p = atomicAdd(&base[c >> 9], 1);
    sorted[p] = ((unsigned)erow[i] << 9) | (unsigned)(c & 511);
  }
}

// ---- degree count: grid (bucket,4); sub-block s scans its slice QUARTER
//      into 512-counter LDS hist -> qcnt[s*stride + node] ----
__global__ __launch_bounds__(256) void k_bcount(const unsigned* __restrict__ sorted,
                                                const int* __restrict__ bbase,
                                                int* __restrict__ qcnt,
                                                int n) {
  __shared__ int h[512];
  int b = blockIdx.x, s = blockIdx.y;
  h[threadIdx.x] = 0; h[threadIdx.x + 256] = 0;
  __syncthreads();
  int s0 = bbase[b], s1 = bbase[b + 1];
  int q = ((s1 - s0) + 3) >> 2;
  int q0 = s0 + s * q, q1 = min(s1, q0 + q);
#pragma unroll 4
  for (int i = q0 + threadIdx.x; i < q1; i += 256)
    atomicAdd(&h[sorted[i] & 511], 1);
  __syncthreads();
  int nodebase = b << 9;
  for (int j = threadIdx.x; j < 512; j += 256) {
    int node = nodebase + j;
    if (node < n) qcnt[s * n + node] = h[j];
  }
}

// ---- per-bucket rowptr + dis: deg = sum_s qcnt; dis = rsqrt(deg+1);
//      rowptr = bbase[b] + in-bucket exclusive prefix of deg ----
__global__ __launch_bounds__(256) void k_rowptr(const int* __restrict__ qcnt,
                                                const int* __restrict__ bbase,
                                                float* __restrict__ dis,
                                                int* __restrict__ rowptr,
                                                int n, int etot) {
  __shared__ int wsum[4];
  int b = blockIdx.x;
  int nodebase = b << 9;
  int n0 = nodebase + 2 * threadIdx.x;
  int n1 = n0 + 1;
  int d0 = 0, d1 = 0;
  if (n0 < n) d0 = qcnt[n0] + qcnt[n + n0] + qcnt[2 * n + n0] + qcnt[3 * n + n0];
  if (n1 < n) d1 = qcnt[n1] + qcnt[n + n1] + qcnt[2 * n + n1] + qcnt[3 * n + n1];
  if (n0 < n) dis[n0] = rsqrtf((float)(d0 + 1));  // +1 self loop
  if (n1 < n) dis[n1] = rsqrtf((float)(d1 + 1));
  int v = d0 + d1;
  int ex = blockScanExclusive256(v, wsum);
  int base = bbase[b] + ex;
  if (n0 < n) rowptr[n0] = base;
  if (n1 < n) rowptr[n1] = base + d0;
  if (b == 0 && threadIdx.x == 0) rowptr[n] = etot;
}

// ---- CSR fill: grid (bucket,4); cursors = rowptr + prefix(qcnt); each
//      sub-block scans only its slice quarter ----
__global__ __launch_bounds__(256) void k_bfill(const unsigned* __restrict__ sorted,
                                               const int* __restrict__ bbase,
                                               const int* __restrict__ rowptr,
                                               const int* __restrict__ qcnt,
                                               int* __restrict__ csr, int n) {
  __shared__ int cur[512];
  int b = blockIdx.x, s = blockIdx.y;
  int nodebase = b << 9;
  for (int j = threadIdx.x; j < 512; j += 256) {
    int node = nodebase + j;
    if (node < n) {
      int c = rowptr[node];
      for (int t = 0; t < s; ++t) c += qcnt[t * n + node];
      cur[j] = c;
    }
  }
  __syncthreads();
  int s0 = bbase[b], s1 = bbase[b + 1];
  int q = ((s1 - s0) + 3) >> 2;
  int q0 = s0 + s * q, q1 = min(s1, q0 + q);
#pragma unroll 4
  for (int i = q0 + threadIdx.x; i < q1; i += 256) {
    unsigned v = sorted[i];
    int pos = atomicAdd(&cur[v & 511], 1);
    csr[pos] = (int)(v >> 9);
  }
}

// ---- layer-1 transform: wave per row, W1 (512x16) held in registers;
//      output fp16 (t1 = (x@W1)*dis) ----
__global__ __launch_bounds__(256) void k_transform1(
    const float* __restrict__ x, const float* __restrict__ W,
    const float* __restrict__ dis, __half* __restrict__ hs, int n) {
  int L = threadIdx.x & 63;
  int wid = blockIdx.x * 4 + (threadIdx.x >> 6);
  int nw = gridDim.x * 4;

  float w[8][16];
  const float4* W4 = reinterpret_cast<const float4*>(W);
#pragma unroll
  for (int i = 0; i < 4; ++i) {
#pragma unroll
    for (int c4 = 0; c4 < 4; ++c4) {
      float4 va = W4[(4 * L + i) * 4 + c4];
      w[i][c4 * 4 + 0] = va.x; w[i][c4 * 4 + 1] = va.y;
      w[i][c4 * 4 + 2] = va.z; w[i][c4 * 4 + 3] = va.w;
      float4 vb = W4[(256 + 4 * L + i) * 4 + c4];
      w[4 + i][c4 * 4 + 0] = vb.x; w[4 + i][c4 * 4 + 1] = vb.y;
      w[4 + i][c4 * 4 + 2] = vb.z; w[4 + i][c4 * 4 + 3] = vb.w;
    }
  }
  int col = ((L & 1) << 3) | ((L & 2) << 1) | ((L & 4) >> 1) | ((L & 8) >> 3);

  for (int r = wid; r < n; r += nw) {
    const float4* xr = reinterpret_cast<const float4*>(x + (size_t)r * 512);
    float4 v0 = xr[L];
    float4 v1 = xr[64 + L];
    float acc[16];
#pragma unroll
    for (int c = 0; c < 16; ++c) {
      float a = v0.x * w[0][c];
      a = fmaf(v0.y, w[1][c], a);
      a = fmaf(v0.z, w[2][c], a);
      a = fmaf(v0.w, w[3][c], a);
      a = fmaf(v1.x, w[4][c], a);
      a = fmaf(v1.y, w[5][c], a);
      a = fmaf(v1.z, w[6][c], a);
      a = fmaf(v1.w, w[7][c], a);
      acc[c] = a;
    }
#pragma unroll
    for (int j = 0; j < 8; ++j) {
      float send = (L & 1) ? acc[j] : acc[j + 8];
      float recv = __shfl_xor(send, 1, 64);
      acc[j] = ((L & 1) ? acc[j + 8] : acc[j]) + recv;
    }
#pragma unroll
    for (int j = 0; j < 4; ++j) {
      float send = (L & 2) ? acc[j] : acc[j + 4];
      float recv = __shfl_xor(send, 2, 64);
      acc[j] = ((L & 2) ? acc[j + 4] : acc[j]) + recv;
    }
#pragma unroll
    for (int j = 0; j < 2; ++j) {
      float send = (L & 4) ? acc[j] : acc[j + 2];
      float recv = __shfl_xor(send, 4, 64);
      acc[j] = ((L & 4) ? acc[j + 2] : acc[j]) + recv;
    }
    {
      float send = (L & 8) ? acc[0] : acc[1];
      float recv = __shfl_xor(send, 8, 64);
      acc[0] = ((L & 8) ? acc[1] : acc[0]) + recv;
    }
    float s = acc[0];
    s += __shfl_xor(s, 16, 64);
    s += __shfl_xor(s, 32, 64);
    if (L < 16) hs[r * 16 + col] = __float2half(s * dis[r]);
  }
}

// ---- common gather: acc = self + sum of neighbor rows (fp16 rows, fp32
//      accumulate). 16-edge unroll, 4 independent accumulators: ~16
//      independent 32B row-loads in flight per wave iteration. ----
__device__ __forceinline__ float gather16(const __half* __restrict__ hs,
                                          const int* __restrict__ rowptr,
                                          const int* __restrict__ csr,
                                          int node, int f) {
  float acc0 = __half2float(hs[(node << 4) + f]);  // self loop (pre-scaled)
  int e0 = rowptr[node], e1 = rowptr[node + 1];
  int e = e0;
  float acc1 = 0.f, acc2 = 0.f, acc3 = 0.f;
  for (; e + 16 <= e1; e += 16) {
    int r0  = csr[e + 0],  r1  = csr[e + 1],  r2  = csr[e + 2],  r3  = csr[e + 3];
    int r4  = csr[e + 4],  r5  = csr[e + 5],  r6  = csr[e + 6],  r7  = csr[e + 7];
    int r8  = csr[e + 8],  r9  = csr[e + 9],  r10 = csr[e + 10], r11 = csr[e + 11];
    int r12 = csr[e + 12], r13 = csr[e + 13], r14 = csr[e + 14], r15 = csr[e + 15];
    __half v0  = hs[(r0  << 4) + f], v1  = hs[(r1  << 4) + f];
    __half v2  = hs[(r2  << 4) + f], v3  = hs[(r3  << 4) + f];
    __half v4  = hs[(r4  << 4) + f], v5  = hs[(r5  << 4) + f];
    __half v6  = hs[(r6  << 4) + f], v7  = hs[(r7  << 4) + f];
    __half v8  = hs[(r8  << 4) + f], v9  = hs[(r9  << 4) + f];
    __half v10 = hs[(r10 << 4) + f], v11 = hs[(r11 << 4) + f];
    __half v12 = hs[(r12 << 4) + f], v13 = hs[(r13 << 4) + f];
    __half v14 = hs[(r14 << 4) + f], v15 = hs[(r15 << 4) + f];
    acc0 += (__half2float(v0)  + __half2float(v1))  + (__half2float(v2)  + __half2float(v3));
    acc1 += (__half2float(v4)  + __half2float(v5))  + (__half2float(v6)  + __half2float(v7));
    acc2 += (__half2float(v8)  + __half2float(v9))  + (__half2float(v10) + __half2float(v11));
    acc3 += (__half2float(v12) + __half2float(v13)) + (__half2float(v14) + __half2float(v15));
  }
  for (; e + 4 <= e1; e += 4) {
    int r0 = csr[e + 0], r1 = csr[e + 1], r2 = csr[e + 2], r3 = csr[e + 3];
    float v0 = __half2float(hs[(r0 << 4) + f]), v1 = __half2float(hs[(r1 << 4) + f]);
    float v2 = __half2float(hs[(r2 << 4) + f]), v3 = __half2float(hs[(r3 << 4) + f]);
    acc0 += (v0 + v1) + (v2 + v3);
  }
  for (; e < e1; ++e) acc0 += __half2float(hs[(csr[e] << 4) + f]);
  return (acc0 + acc1) + (acc2 + acc3);
}

// out = relu(dis*acc + b) * dis   (layer-1 agg, prescaled for next gather)
__global__ __launch_bounds__(256) void k_agg_rb(
    const __half* __restrict__ hs, const int* __restrict__ rowptr,
    const int* __restrict__ csr, const float* __restrict__ dis,
    const float* __restrict__ b, __half* __restrict__ out, int n) {
  int node = blockIdx.x * 16 + threadIdx.x / 16;
  int f = threadIdx.x % 16;
  if (node >= n) return;
  float acc = gather16(hs, rowptr, csr, node, f);
  float d = dis[node];
  float t = fmaxf(fmaf(d, acc, b[f]), 0.f);
  out[(node << 4) + f] = __float2half(t * d);
}

// mid: t3 = (relu((dis*acc)@W2 + b2) @ W3) * dis   -- 16->32->16 in-register
__global__ __launch_bounds__(256) void k_agg_mid(
    const __half* __restrict__ hs, const int* __restrict__ rowptr,
    const int* __restrict__ csr, const float* __restrict__ dis,
    const float* __restrict__ W2, const float* __restrict__ b2,
    const float* __restrict__ W3, __half* __restrict__ out, int n) {
  __shared__ float w2s[512];  // [16][32]
  __shared__ float w3s[512];  // [32][16]
  __shared__ float b2s[32];
  for (int i = threadIdx.x; i < 512; i += 256) { w2s[i] = W2[i]; w3s[i] = W3[i]; }
  if (threadIdx.x < 32) b2s[threadIdx.x] = b2[threadIdx.x];
  __syncthreads();
  int node = blockIdx.x * 16 + threadIdx.x / 16;
  int f = threadIdx.x % 16;
  if (node >= n) return;
  float acc = gather16(hs, rowptr, csr, node, f);
  float d = dis[node];
  float v = d * acc;  // g2[f]
  int base = threadIdx.x & 48;  // 16-group base lane in wave
  float a0 = b2s[f], a1 = b2s[f + 16];
#pragma unroll
  for (int k = 0; k < 16; ++k) {
    float vk = __shfl(v, base + k, 64);
    a0 = fmaf(vk, w2s[k * 32 + f], a0);
    a1 = fmaf(vk, w2s[k * 32 + 16 + f], a1);
  }
  a0 = fmaxf(a0, 0.f);
  a1 = fmaxf(a1, 0.f);
  float t = 0.f;
#pragma unroll
  for (int c = 0; c < 16; ++c) {
    float h0 = __shfl(a0, base + c, 64);
    float h1 = __shfl(a1, base + c, 64);
    t = fmaf(h0, w3s[c * 16 + f], t);
    t = fmaf(h1, w3s[(c + 16) * 16 + f], t);
  }
  out[(node << 4) + f] = __float2half(t * d);
}

// final: h = relu(dis*acc + b3) -> outh;  out = h@Wc + bc -> outc
__global__ __launch_bounds__(256) void k_agg_out(
    const __half* __restrict__ hs, const int* __restrict__ rowptr,
    const int* __restrict__ csr, const float* __restrict__ dis,
    const float* __restrict__ b3, const float* __restrict__ Wc,
    const float* __restrict__ bc, float* __restrict__ outh,
    float* __restrict__ outc, int n) {
  __shared__ float wcs[256];  // [16][16]
  __shared__ float b3s[16];
  __shared__ float bcs[16];
  if (threadIdx.x < 256) wcs[threadIdx.x] = Wc[threadIdx.x];
  if (threadIdx.x < 16) { b3s[threadIdx.x] = b3[threadIdx.x]; bcs[threadIdx.x] = bc[threadIdx.x]; }
  __syncthreads();
  int node = blockIdx.x * 16 + threadIdx.x / 16;
  int f = threadIdx.x % 16;
  if (node >= n) return;
  float acc = gather16(hs, rowptr, csr, node, f);
  float d = dis[node];
  float h = fmaxf(fmaf(d, acc, b3s[f]), 0.f);
  outh[(node << 4) + f] = h;
  int base = threadIdx.x & 48;
  float o = bcs[f];
#pragma unroll
  for (int k = 0; k < 16; ++k) {
    float hk = __shfl(h, base + k, 64);
    o = fmaf(hk, wcs[k * 16 + f], o);
  }
  outc[(node << 4) + f] = o;
}

extern "C" void kernel_launch(void* const* d_in, const int* in_sizes, int n_in,
                              void* d_out, int out_size, void* d_ws, size_t ws_size,
                              hipStream_t stream) {
  (void)n_in; (void)out_size;
  const float* x  = (const float*)d_in[0];
  const int*   ei = (const int*)d_in[1];
  const float* W1 = (const float*)d_in[2];
  const float* b1 = (const float*)d_in[3];
  const float* W2 = (const float*)d_in[4];
  const float* b2 = (const float*)d_in[5];
  const float* W3 = (const float*)d_in[6];
  const float* b3 = (const float*)d_in[7];
  const float* Wc = (const float*)d_in[8];
  const float* bc = (const float*)d_in[9];

  const int F = 512;
  int N = in_sizes[0] / F;
  int E = in_sizes[1] / 2;
  const int* erow = ei;        // sources
  const int* ecol = ei + E;    // targets
  int NB = (N + 511) >> 9;     // buckets of 512 nodes (N<=131072)
  const int G = 1024;          // edge-scan grid (4 blocks/CU)
  int chunk = (E + G - 1) / G;

  auto align = [](size_t v) { return (v + 255) & ~(size_t)255; };
  char* p = (char*)d_ws;
  int*   cntmat = (int*)p;   p += align((size_t)NB * G * 4);
  int*   colsum = (int*)p;   p += align(256 * 4);
  int*   bbase  = (int*)p;   p += align(257 * 4);
  int*   qcnt   = (int*)p;   p += align((size_t)4 * N * 4);
  float* dis    = (float*)p; p += align((size_t)N * 4);
  int*   rowptr = (int*)p;   p += align(((size_t)N + 1) * 4);
  int*   csr    = (int*)p;   p += align((size_t)E * 4);
  unsigned* sorted = (unsigned*)p; p += align((size_t)E * 4);
  if ((size_t)(p - (char*)d_ws) > ws_size) return;  // fail visibly

  // bufA/bufB alias `sorted` (dead after CSR build). E*4 >= 2*N*16*2 here.
  __half* bufA = (__half*)sorted;
  __half* bufB = (__half*)sorted + (size_t)N * 16;

  float* outc = (float*)d_out;                   // [N,16] classifier out
  float* outh = (float*)d_out + (size_t)N * 16;  // [N,16] h

  // ---- CSR build ----
  k_bhist<<<G, 256, 0, stream>>>(ecol, cntmat, E, chunk, NB);
  k_colscan<<<NB, 256, 0, stream>>>(cntmat, colsum, G);
  k_bscan<<<1, 256, 0, stream>>>(colsum, bbase, NB, E);
  k_bscatter<<<G, 256, 0, stream>>>(erow, ecol, cntmat, bbase, sorted, E, chunk, NB);
  k_bcount<<<dim3(NB, 4), 256, 0, stream>>>(sorted, bbase, qcnt, N);
  k_rowptr<<<NB, 256, 0, stream>>>(qcnt, bbase, dis, rowptr, N, E);
  k_bfill<<<dim3(NB, 4), 256, 0, stream>>>(sorted, bbase, rowptr, qcnt, csr, N);

  // ---- layers ----
  // t1 = (x@W1)*dis  (fp16)
  k_transform1<<<2048, 256, 0, stream>>>(x, W1, dis, bufA, N);
  // hs1 = relu(dis*agg(t1)+b1)*dis  (fp16)
  k_agg_rb<<<(N + 15) / 16, 256, 0, stream>>>(bufA, rowptr, csr, dis, b1, bufB, N);
  // t3 = (relu((dis*agg(hs1))@W2+b2)@W3)*dis  (fp16)
  k_agg_mid<<<(N + 15) / 16, 256, 0, stream>>>(bufB, rowptr, csr, dis, W2, b2, W3, bufA, N);
  // h = relu(dis*agg(t3)+b3) -> outh;  out = h@Wc+bc -> outc  (fp32 outputs)
  k_agg_out<<<(N + 15) / 16, 256, 0, stream>>>(bufA, rowptr, csr, dis, b3, Wc, bc, outh, outc, N);
}

// Round 3
// 361.671 us; speedup vs baseline: 1.3530x; 1.0583x over previous
//
#include <hip/hip_runtime.h>
#include <hip/hip_bf16.h>
#include <hip/hip_fp16.h>
#include <stdint.h>

// ---------------------------------------------------------------------------
// GCN forward on MI355X.
//   CSR build via 196-bucket counting sort (bucket = col>>9, 512 nodes each).
//     k_bhist   : chunked edge scan, LDS hist, writes cntmat[b][g] (b-major)
//     k_colscan : per-bucket exclusive scan of cntmat column over g
//     k_bscan   : exclusive scan of bucket totals -> bbase
//     k_scat_xf : FUSED single-pass scatter + layer-1 transform.
//                 Phase 1: counting-sort scatter (base[b]=bbase[b]+cntmat[b][g]
//                 in LDS as cursor), packed payload (row<<9 | col&511).
//                 Phase 2: t1raw = x @ W1 (wave-per-row, W1 in regs, fp16 out,
//                 dis NOT applied yet -- dis doesn't exist yet).
//                 G=4096 blocks -> ~5 block generations/CU so scatter's
//                 latency phase and the 204.8MB x-stream overlap.
//     k_pass2   : one block per bucket (512 thr): LDS 512-hist of sorted
//                 slice -> LDS scan -> rowptr = bbase[b]+prefix, dis =
//                 rsqrt(deg+1), scale t1raw *= dis (bucket rows are
//                 contiguous), then cursor-fill csr. Replaces the old
//                 k_bcount/k_rowptr/k_bfill (one fewer pass over sorted,
//                 no qcnt round-trip).
//   Layers (agg commutes with dense: A(XW)=(AX)W; all gathers width 16; the
//   16->32->16 chain and the classifier are fused into agg epilogues via
//   16-lane shuffle broadcasts -- h2 is never materialized):
//     t1  = (x @ W1) * dis                        (k_scat_xf + k_pass2)
//     hs1 = relu(dis*gather(t1) + b1) * dis       (k_agg_rb)
//     t3  = (relu((dis*gather(hs1))@W2+b2)@W3)*dis (k_agg_mid, fused)
//     h   = relu(dis*gather(t3) + b3) -> outh
//     out = h @ Wc + bc               -> outc      (k_agg_out, fused)
//   Gathered arrays (t1, hs1, t3) are stored FP16: 3.2MB each -> fits the
//   4MB per-XCD L2. Random row reads are 32B, accumulation fp32. gather is
//   16-edge unrolled with 4 independent accumulators (~16 lines in flight).
//   No fp atomics anywhere. 8 kernel launches total.
// ---------------------------------------------------------------------------

__device__ __forceinline__ int blockScanExclusive256(int v, int* wsum) {
  int lane = threadIdx.x & 63;
  int wid  = threadIdx.x >> 6;
  int inc = v;
#pragma unroll
  for (int d = 1; d < 64; d <<= 1) {
    int y = __shfl_up(inc, d, 64);
    if (lane >= d) inc += y;
  }
  if (lane == 63) wsum[wid] = inc;
  __syncthreads();
  if (threadIdx.x == 0) {
    int s = 0;
#pragma unroll
    for (int w = 0; w < 4; ++w) { int t = wsum[w]; wsum[w] = s; s += t; }
  }
  __syncthreads();
  return inc - v + wsum[wid];
}

__device__ __forceinline__ int blockScanExclusive512(int v, int* wsum) {
  int lane = threadIdx.x & 63;
  int wid  = threadIdx.x >> 6;  // 0..7
  int inc = v;
#pragma unroll
  for (int d = 1; d < 64; d <<= 1) {
    int y = __shfl_up(inc, d, 64);
    if (lane >= d) inc += y;
  }
  if (lane == 63) wsum[wid] = inc;
  __syncthreads();
  if (threadIdx.x == 0) {
    int s = 0;
#pragma unroll
    for (int w = 0; w < 8; ++w) { int t = wsum[w]; wsum[w] = s; s += t; }
  }
  __syncthreads();
  return inc - v + wsum[wid];
}

// ---- per-block bucket histogram -> cntmat[b*G + g] (bucket-major) ----
__global__ __launch_bounds__(256) void k_bhist(const int* __restrict__ ecol,
                                               int* __restrict__ cntmat,
                                               int e, int chunk, int nb) {
  __shared__ int h[256];
  h[threadIdx.x] = 0;
  __syncthreads();
  int g = blockIdx.x, G = gridDim.x;
  int s0 = g * chunk;
  int s1 = min(e, s0 + chunk);
  int i = s0 + threadIdx.x;
  for (; i + 768 < s1; i += 1024) {
    int c0 = ecol[i], c1 = ecol[i + 256], c2 = ecol[i + 512], c3 = ecol[i + 768];
    atomicAdd(&h[c0 >> 9], 1);
    atomicAdd(&h[c1 >> 9], 1);
    atomicAdd(&h[c2 >> 9], 1);
    atomicAdd(&h[c3 >> 9], 1);
  }
  for (; i < s1; i += 256) atomicAdd(&h[ecol[i] >> 9], 1);
  __syncthreads();
  for (int b = threadIdx.x; b < nb; b += 256) cntmat[b * G + g] = h[b];
}

// ---- per-bucket column scan over g; column total -> colsum[b] ----
__global__ __launch_bounds__(256) void k_colscan(int* __restrict__ cntmat,
                                                 int* __restrict__ colsum, int G) {
  __shared__ int wsum[4];
  __shared__ int carry_s;
  int b = blockIdx.x;
  if (threadIdx.x == 0) carry_s = 0;
  __syncthreads();
  for (int base = 0; base < G; base += 256) {
    int i = base + threadIdx.x;
    int v = (i < G) ? cntmat[b * G + i] : 0;
    int ex = blockScanExclusive256(v, wsum);
    int c = carry_s;
    __syncthreads();
    if (i < G) cntmat[b * G + i] = ex + c;
    if (threadIdx.x == 255) carry_s = c + ex + v;
    __syncthreads();
  }
  if (threadIdx.x == 0) colsum[b] = carry_s;
}

// ---- bucket exclusive scan (1 block) ----
__global__ __launch_bounds__(256) void k_bscan(const int* __restrict__ colsum,
                                               int* __restrict__ bbase,
                                               int nb, int etot) {
  __shared__ int wsum[4];
  __shared__ int carry_s;
  if (threadIdx.x == 0) carry_s = 0;
  __syncthreads();
  for (int base = 0; base < nb; base += 256) {
    int i = base + threadIdx.x;
    int v = (i < nb) ? colsum[i] : 0;
    int ex = blockScanExclusive256(v, wsum);
    int c = carry_s;
    __syncthreads();
    if (i < nb) bbase[i] = ex + c;
    if (threadIdx.x == 255) carry_s = c + ex + v;
    __syncthreads();
  }
  if (threadIdx.x == 0) bbase[nb] = etot;
}

// ---- FUSED: counting-sort scatter + layer-1 transform (no dis) ----
__global__ __launch_bounds__(256) void k_scat_xf(
    const int* __restrict__ erow, const int* __restrict__ ecol,
    const int* __restrict__ cntmat, const int* __restrict__ bbase,
    unsigned* __restrict__ sorted, int e, int chunk, int nb,
    const float* __restrict__ x, const float* __restrict__ W,
    __half* __restrict__ t1raw, int n) {
  __shared__ int base[256];
  int g = blockIdx.x, G = gridDim.x;
  for (int b = threadIdx.x; b < nb; b += 256)
    base[b] = bbase[b] + cntmat[b * G + g];
  __syncthreads();
  int s0 = g * chunk;
  int s1 = min(e, s0 + chunk);
  {
    int i = s0 + threadIdx.x;
    for (; i + 768 < s1; i += 1024) {
      int c0 = ecol[i],       c1 = ecol[i + 256], c2 = ecol[i + 512], c3 = ecol[i + 768];
      int r0 = erow[i],       r1 = erow[i + 256], r2 = erow[i + 512], r3 = erow[i + 768];
      int p0 = atomicAdd(&base[c0 >> 9], 1);
      int p1 = atomicAdd(&base[c1 >> 9], 1);
      int p2 = atomicAdd(&base[c2 >> 9], 1);
      int p3 = atomicAdd(&base[c3 >> 9], 1);
      sorted[p0] = ((unsigned)r0 << 9) | (unsigned)(c0 & 511);
      sorted[p1] = ((unsigned)r1 << 9) | (unsigned)(c1 & 511);
      sorted[p2] = ((unsigned)r2 << 9) | (unsigned)(c2 & 511);
      sorted[p3] = ((unsigned)r3 << 9) | (unsigned)(c3 & 511);
    }
    for (; i < s1; i += 256) {
      int c = ecol[i];
      int p = atomicAdd(&base[c >> 9], 1);
      sorted[p] = ((unsigned)erow[i] << 9) | (unsigned)(c & 511);
    }
  }

  // ---- transform phase: wave per row, W (512x16) in registers ----
  int L = threadIdx.x & 63;
  int wid = blockIdx.x * 4 + (threadIdx.x >> 6);
  int nw = gridDim.x * 4;

  float w[8][16];
  const float4* W4 = reinterpret_cast<const float4*>(W);
#pragma unroll
  for (int i = 0; i < 4; ++i) {
#pragma unroll
    for (int c4 = 0; c4 < 4; ++c4) {
      float4 va = W4[(4 * L + i) * 4 + c4];
      w[i][c4 * 4 + 0] = va.x; w[i][c4 * 4 + 1] = va.y;
      w[i][c4 * 4 + 2] = va.z; w[i][c4 * 4 + 3] = va.w;
      float4 vb = W4[(256 + 4 * L + i) * 4 + c4];
      w[4 + i][c4 * 4 + 0] = vb.x; w[4 + i][c4 * 4 + 1] = vb.y;
      w[4 + i][c4 * 4 + 2] = vb.z; w[4 + i][c4 * 4 + 3] = vb.w;
    }
  }
  int col = ((L & 1) << 3) | ((L & 2) << 1) | ((L & 4) >> 1) | ((L & 8) >> 3);

  for (int r = wid; r < n; r += nw) {
    const float4* xr = reinterpret_cast<const float4*>(x + (size_t)r * 512);
    float4 v0 = xr[L];
    float4 v1 = xr[64 + L];
    float acc[16];
#pragma unroll
    for (int c = 0; c < 16; ++c) {
      float a = v0.x * w[0][c];
      a = fmaf(v0.y, w[1][c], a);
      a = fmaf(v0.z, w[2][c], a);
      a = fmaf(v0.w, w[3][c], a);
      a = fmaf(v1.x, w[4][c], a);
      a = fmaf(v1.y, w[5][c], a);
      a = fmaf(v1.z, w[6][c], a);
      a = fmaf(v1.w, w[7][c], a);
      acc[c] = a;
    }
#pragma unroll
    for (int j = 0; j < 8; ++j) {
      float send = (L & 1) ? acc[j] : acc[j + 8];
      float recv = __shfl_xor(send, 1, 64);
      acc[j] = ((L & 1) ? acc[j + 8] : acc[j]) + recv;
    }
#pragma unroll
    for (int j = 0; j < 4; ++j) {
      float send = (L & 2) ? acc[j] : acc[j + 4];
      float recv = __shfl_xor(send, 2, 64);
      acc[j] = ((L & 2) ? acc[j + 4] : acc[j]) + recv;
    }
#pragma unroll
    for (int j = 0; j < 2; ++j) {
      float send = (L & 4) ? acc[j] : acc[j + 2];
      float recv = __shfl_xor(send, 4, 64);
      acc[j] = ((L & 4) ? acc[j + 2] : acc[j]) + recv;
    }
    {
      float send = (L & 8) ? acc[0] : acc[1];
      float recv = __shfl_xor(send, 8, 64);
      acc[0] = ((L & 8) ? acc[1] : acc[0]) + recv;
    }
    float s = acc[0];
    s += __shfl_xor(s, 16, 64);
    s += __shfl_xor(s, 32, 64);
    if (L < 16) t1raw[r * 16 + col] = __float2half(s);
  }
}

// ---- pass2: per-bucket hist + scan + rowptr/dis + t1 scale + csr fill ----
__global__ __launch_bounds__(512) void k_pass2(const unsigned* __restrict__ sorted,
                                               const int* __restrict__ bbase,
                                               float* __restrict__ dis,
                                               int* __restrict__ rowptr,
                                               __half* __restrict__ t1,
                                               int* __restrict__ csr,
                                               int n, int etot) {
  __shared__ int hist[512];
  __shared__ int cur[512];
  __shared__ int wsum[8];
  int b = blockIdx.x;
  hist[threadIdx.x] = 0;
  __syncthreads();
  int s0 = bbase[b], s1 = bbase[b + 1];
  for (int i = s0 + threadIdx.x; i < s1; i += 512)
    atomicAdd(&hist[sorted[i] & 511], 1);
  __syncthreads();
  int j = threadIdx.x;
  int node = (b << 9) + j;
  int deg = hist[j];
  int ex = blockScanExclusive512(deg, wsum);
  float dv = rsqrtf((float)(deg + 1));  // +1 self loop
  cur[j] = s0 + ex;
  if (node < n) {
    dis[node] = dv;
    rowptr[node] = s0 + ex;
    // scale this node's t1 row in place (bucket rows contiguous, streaming)
    __half2* t2 = reinterpret_cast<__half2*>(t1 + ((size_t)node << 4));
#pragma unroll
    for (int q = 0; q < 8; ++q) {
      float2 fv = __half22float2(t2[q]);
      fv.x *= dv; fv.y *= dv;
      t2[q] = __float22half2_rn(fv);
    }
  }
  if (b == 0 && threadIdx.x == 0) rowptr[n] = etot;
  __syncthreads();
  for (int i = s0 + threadIdx.x; i < s1; i += 512) {
    unsigned v = sorted[i];
    int pos = atomicAdd(&cur[v & 511], 1);
    csr[pos] = (int)(v >> 9);
  }
}

// ---- common gather: acc = self + sum of neighbor rows (fp16 rows, fp32
//      accumulate). 16-edge unroll, 4 independent accumulators: ~16
//      independent 32B row-loads in flight per wave iteration. ----
__device__ __forceinline__ float gather16(const __half* __restrict__ hs,
                                          const int* __restrict__ rowptr,
                                          const int* __restrict__ csr,
                                          int node, int f) {
  float acc0 = __half2float(hs[(node << 4) + f]);  // self loop (pre-scaled)
  int e0 = rowptr[node], e1 = rowptr[node + 1];
  int e = e0;
  float acc1 = 0.f, acc2 = 0.f, acc3 = 0.f;
  for (; e + 16 <= e1; e += 16) {
    int r0  = csr[e + 0],  r1  = csr[e + 1],  r2  = csr[e + 2],  r3  = csr[e + 3];
    int r4  = csr[e + 4],  r5  = csr[e + 5],  r6  = csr[e + 6],  r7  = csr[e + 7];
    int r8  = csr[e + 8],  r9  = csr[e + 9],  r10 = csr[e + 10], r11 = csr[e + 11];
    int r12 = csr[e + 12], r13 = csr[e + 13], r14 = csr[e + 14], r15 = csr[e + 15];
    __half v0  = hs[(r0  << 4) + f], v1  = hs[(r1  << 4) + f];
    __half v2  = hs[(r2  << 4) + f], v3  = hs[(r3  << 4) + f];
    __half v4  = hs[(r4  << 4) + f], v5  = hs[(r5  << 4) + f];
    __half v6  = hs[(r6  << 4) + f], v7  = hs[(r7  << 4) + f];
    __half v8  = hs[(r8  << 4) + f], v9  = hs[(r9  << 4) + f];
    __half v10 = hs[(r10 << 4) + f], v11 = hs[(r11 << 4) + f];
    __half v12 = hs[(r12 << 4) + f], v13 = hs[(r13 << 4) + f];
    __half v14 = hs[(r14 << 4) + f], v15 = hs[(r15 << 4) + f];
    acc0 += (__half2float(v0)  + __half2float(v1))  + (__half2float(v2)  + __half2float(v3));
    acc1 += (__half2float(v4)  + __half2float(v5))  + (__half2float(v6)  + __half2float(v7));
    acc2 += (__half2float(v8)  + __half2float(v9))  + (__half2float(v10) + __half2float(v11));
    acc3 += (__half2float(v12) + __half2float(v13)) + (__half2float(v14) + __half2float(v15));
  }
  for (; e + 4 <= e1; e += 4) {
    int r0 = csr[e + 0], r1 = csr[e + 1], r2 = csr[e + 2], r3 = csr[e + 3];
    float v0 = __half2float(hs[(r0 << 4) + f]), v1 = __half2float(hs[(r1 << 4) + f]);
    float v2 = __half2float(hs[(r2 << 4) + f]), v3 = __half2float(hs[(r3 << 4) + f]);
    acc0 += (v0 + v1) + (v2 + v3);
  }
  for (; e < e1; ++e) acc0 += __half2float(hs[(csr[e] << 4) + f]);
  return (acc0 + acc1) + (acc2 + acc3);
}

// out = relu(dis*acc + b) * dis   (layer-1 agg, prescaled for next gather)
__global__ __launch_bounds__(256) void k_agg_rb(
    const __half* __restrict__ hs, const int* __restrict__ rowptr,
    const int* __restrict__ csr, const float* __restrict__ dis,
    const float* __restrict__ b, __half* __restrict__ out, int n) {
  int node = blockIdx.x * 16 + threadIdx.x / 16;
  int f = threadIdx.x % 16;
  if (node >= n) return;
  float acc = gather16(hs, rowptr, csr, node, f);
  float d = dis[node];
  float t = fmaxf(fmaf(d, acc, b[f]), 0.f);
  out[(node << 4) + f] = __float2half(t * d);
}

// mid: t3 = (relu((dis*acc)@W2 + b2) @ W3) * dis   -- 16->32->16 in-register
__global__ __launch_bounds__(256) void k_agg_mid(
    const __half* __restrict__ hs, const int* __restrict__ rowptr,
    const int* __restrict__ csr, const float* __restrict__ dis,
    const float* __restrict__ W2, const float* __restrict__ b2,
    const float* __restrict__ W3, __half* __restrict__ out, int n) {
  __shared__ float w2s[512];  // [16][32]
  __shared__ float w3s[512];  // [32][16]
  __shared__ float b2s[32];
  for (int i = threadIdx.x; i < 512; i += 256) { w2s[i] = W2[i]; w3s[i] = W3[i]; }
  if (threadIdx.x < 32) b2s[threadIdx.x] = b2[threadIdx.x];
  __syncthreads();
  int node = blockIdx.x * 16 + threadIdx.x / 16;
  int f = threadIdx.x % 16;
  if (node >= n) return;
  float acc = gather16(hs, rowptr, csr, node, f);
  float d = dis[node];
  float v = d * acc;  // g2[f]
  int base = threadIdx.x & 48;  // 16-group base lane in wave
  float a0 = b2s[f], a1 = b2s[f + 16];
#pragma unroll
  for (int k = 0; k < 16; ++k) {
    float vk = __shfl(v, base + k, 64);
    a0 = fmaf(vk, w2s[k * 32 + f], a0);
    a1 = fmaf(vk, w2s[k * 32 + 16 + f], a1);
  }
  a0 = fmaxf(a0, 0.f);
  a1 = fmaxf(a1, 0.f);
  float t = 0.f;
#pragma unroll
  for (int c = 0; c < 16; ++c) {
    float h0 = __shfl(a0, base + c, 64);
    float h1 = __shfl(a1, base + c, 64);
    t = fmaf(h0, w3s[c * 16 + f], t);
    t = fmaf(h1, w3s[(c + 16) * 16 + f], t);
  }
  out[(node << 4) + f] = __float2half(t * d);
}

// final: h = relu(dis*acc + b3) -> outh;  out = h@Wc + bc -> outc
__global__ __launch_bounds__(256) void k_agg_out(
    const __half* __restrict__ hs, const int* __restrict__ rowptr,
    const int* __restrict__ csr, const float* __restrict__ dis,
    const float* __restrict__ b3, const float* __restrict__ Wc,
    const float* __restrict__ bc, float* __restrict__ outh,
    float* __restrict__ outc, int n) {
  __shared__ float wcs[256];  // [16][16]
  __shared__ float b3s[16];
  __shared__ float bcs[16];
  if (threadIdx.x < 256) wcs[threadIdx.x] = Wc[threadIdx.x];
  if (threadIdx.x < 16) { b3s[threadIdx.x] = b3[threadIdx.x]; bcs[threadIdx.x] = bc[threadIdx.x]; }
  __syncthreads();
  int node = blockIdx.x * 16 + threadIdx.x / 16;
  int f = threadIdx.x % 16;
  if (node >= n) return;
  float acc = gather16(hs, rowptr, csr, node, f);
  float d = dis[node];
  float h = fmaxf(fmaf(d, acc, b3s[f]), 0.f);
  outh[(node << 4) + f] = h;
  int base = threadIdx.x & 48;
  float o = bcs[f];
#pragma unroll
  for (int k = 0; k < 16; ++k) {
    float hk = __shfl(h, base + k, 64);
    o = fmaf(hk, wcs[k * 16 + f], o);
  }
  outc[(node << 4) + f] = o;
}

extern "C" void kernel_launch(void* const* d_in, const int* in_sizes, int n_in,
                              void* d_out, int out_size, void* d_ws, size_t ws_size,
                              hipStream_t stream) {
  (void)n_in; (void)out_size;
  const float* x  = (const float*)d_in[0];
  const int*   ei = (const int*)d_in[1];
  const float* W1 = (const float*)d_in[2];
  const float* b1 = (const float*)d_in[3];
  const float* W2 = (const float*)d_in[4];
  const float* b2 = (const float*)d_in[5];
  const float* W3 = (const float*)d_in[6];
  const float* b3 = (const float*)d_in[7];
  const float* Wc = (const float*)d_in[8];
  const float* bc = (const float*)d_in[9];

  const int F = 512;
  int N = in_sizes[0] / F;
  int E = in_sizes[1] / 2;
  const int* erow = ei;        // sources
  const int* ecol = ei + E;    // targets
  int NB = (N + 511) >> 9;     // buckets of 512 nodes (N<=131072)
  const int G = 4096;          // edge-scan grid (deep oversubscription so
                               // scatter & transform phases mix across gens)
  int chunk = (E + G - 1) / G;

  auto align = [](size_t v) { return (v + 255) & ~(size_t)255; };
  char* p = (char*)d_ws;
  int*   cntmat = (int*)p;   p += align((size_t)NB * G * 4);
  int*   colsum = (int*)p;   p += align(256 * 4);
  int*   bbase  = (int*)p;   p += align(257 * 4);
  float* dis    = (float*)p; p += align((size_t)N * 4);
  int*   rowptr = (int*)p;   p += align(((size_t)N + 1) * 4);
  int*   csr    = (int*)p;   p += align((size_t)E * 4);
  unsigned* sorted = (unsigned*)p; p += align((size_t)E * 4);
  // bufA no longer aliases sorted (sorted is live while t1 is written)
  __half* bufA = (__half*)p; p += align((size_t)N * 16 * 2);
  __half* bufB = (__half*)p; p += align((size_t)N * 16 * 2);
  if ((size_t)(p - (char*)d_ws) > ws_size) return;  // fail visibly

  float* outc = (float*)d_out;                   // [N,16] classifier out
  float* outh = (float*)d_out + (size_t)N * 16;  // [N,16] h

  // ---- CSR build + fused layer-1 transform ----
  k_bhist<<<G, 256, 0, stream>>>(ecol, cntmat, E, chunk, NB);
  k_colscan<<<NB, 256, 0, stream>>>(cntmat, colsum, G);
  k_bscan<<<1, 256, 0, stream>>>(colsum, bbase, NB, E);
  // scatter + t1raw = x@W1 (unscaled)
  k_scat_xf<<<G, 256, 0, stream>>>(erow, ecol, cntmat, bbase, sorted, E, chunk,
                                   NB, x, W1, bufA, N);
  // hist+scan+rowptr+dis, t1 *= dis, csr fill
  k_pass2<<<NB, 512, 0, stream>>>(sorted, bbase, dis, rowptr, bufA, csr, N, E);

  // ---- layers ----
  // hs1 = relu(dis*agg(t1)+b1)*dis  (fp16)
  k_agg_rb<<<(N + 15) / 16, 256, 0, stream>>>(bufA, rowptr, csr, dis, b1, bufB, N);
  // t3 = (relu((dis*agg(hs1))@W2+b2)@W3)*dis  (fp16)
  k_agg_mid<<<(N + 15) / 16, 256, 0, stream>>>(bufB, rowptr, csr, dis, W2, b2, W3, bufA, N);
  // h = relu(dis*agg(t3)+b3) -> outh;  out = h@Wc+bc -> outc  (fp32 outputs)
  k_agg_out<<<(N + 15) / 16, 256, 0, stream>>>(bufA, rowptr, csr, dis, b3, Wc, bc, outh, outc, N);
}

// Round 4
// 318.509 us; speedup vs baseline: 1.5364x; 1.1355x over previous
//
#include <hip/hip_runtime.h>
#include <hip/hip_bf16.h>
#include <hip/hip_fp16.h>
#include <stdint.h>

// ---------------------------------------------------------------------------
// GCN forward on MI355X.
//   CSR build via 196-bucket counting sort (bucket = col>>9, 512 nodes each).
//     k_bhist   : G=512 chunked edge scan, LDS hist -> cntmat[g][b] (g-major:
//                 each scatter block later reads its 196 offsets contiguously)
//     k_colscan : per-bucket exclusive scan of cntmat column over g
//     k_bscan   : exclusive scan of bucket totals -> bbase
//     k_scat_xf : HETEROGENEOUS-ROLE fused kernel.
//                 blocks [0,GS)     : counting-sort scatter. GS=512 ->
//                   chunk=12.5K, per-(block,bucket) write runs = 64 edges =
//                   256B contiguous (G=4096 gave 32B runs -> cross-XCD
//                   partial-line ping-pong; that was the round-3 regression).
//                 blocks [GS,GS+GT) : t1raw = x @ W1 (wave-per-row, W1 in
//                   regs, fp16 out, dis applied later in k_pass2).
//                 Roles are independent -> CU scheduler co-resides them and
//                 the 204.8MB x-stream runs inside the scatter's write-stall
//                 bubbles (intra-block phase fusion gave no overlap: all
//                 resident blocks were in the same phase at the same time).
//     k_pass2   : one block per bucket (512 thr): LDS 512-hist of sorted
//                 slice -> LDS scan -> rowptr = bbase[b]+prefix, dis =
//                 rsqrt(deg+1), scale t1raw *= dis, cursor-fill csr.
//   Layers (agg commutes with dense: A(XW)=(AX)W; all gathers width 16; the
//   16->32->16 chain and the classifier are fused into agg epilogues via
//   16-lane shuffle broadcasts -- h2 is never materialized):
//     t1  = (x @ W1) * dis                        (k_scat_xf + k_pass2)
//     hs1 = relu(dis*gather(t1) + b1) * dis       (k_agg_rb)
//     t3  = (relu((dis*gather(hs1))@W2+b2)@W3)*dis (k_agg_mid, fused)
//     h   = relu(dis*gather(t3) + b3) -> outh
//     out = h @ Wc + bc               -> outc      (k_agg_out, fused)
//   Gathered arrays (t1, hs1, t3) are stored FP16: 3.2MB each -> fits the
//   4MB per-XCD L2. Random row reads are 32B, accumulation fp32. gather is
//   16-edge unrolled with 4 independent accumulators (~16 lines in flight).
//   No fp atomics anywhere. 8 kernel launches total.
// ---------------------------------------------------------------------------

__device__ __forceinline__ int blockScanExclusive256(int v, int* wsum) {
  int lane = threadIdx.x & 63;
  int wid  = threadIdx.x >> 6;
  int inc = v;
#pragma unroll
  for (int d = 1; d < 64; d <<= 1) {
    int y = __shfl_up(inc, d, 64);
    if (lane >= d) inc += y;
  }
  if (lane == 63) wsum[wid] = inc;
  __syncthreads();
  if (threadIdx.x == 0) {
    int s = 0;
#pragma unroll
    for (int w = 0; w < 4; ++w) { int t = wsum[w]; wsum[w] = s; s += t; }
  }
  __syncthreads();
  return inc - v + wsum[wid];
}

__device__ __forceinline__ int blockScanExclusive512(int v, int* wsum) {
  int lane = threadIdx.x & 63;
  int wid  = threadIdx.x >> 6;  // 0..7
  int inc = v;
#pragma unroll
  for (int d = 1; d < 64; d <<= 1) {
    int y = __shfl_up(inc, d, 64);
    if (lane >= d) inc += y;
  }
  if (lane == 63) wsum[wid] = inc;
  __syncthreads();
  if (threadIdx.x == 0) {
    int s = 0;
#pragma unroll
    for (int w = 0; w < 8; ++w) { int t = wsum[w]; wsum[w] = s; s += t; }
  }
  __syncthreads();
  return inc - v + wsum[wid];
}

// ---- per-block bucket histogram -> cntmat[g*nb + b] (g-major) ----
__global__ __launch_bounds__(256) void k_bhist(const int* __restrict__ ecol,
                                               int* __restrict__ cntmat,
                                               int e, int chunk, int nb) {
  __shared__ int h[256];
  h[threadIdx.x] = 0;
  __syncthreads();
  int g = blockIdx.x;
  int s0 = g * chunk;
  int s1 = min(e, s0 + chunk);
  int i = s0 + threadIdx.x;
  for (; i + 768 < s1; i += 1024) {
    int c0 = ecol[i], c1 = ecol[i + 256], c2 = ecol[i + 512], c3 = ecol[i + 768];
    atomicAdd(&h[c0 >> 9], 1);
    atomicAdd(&h[c1 >> 9], 1);
    atomicAdd(&h[c2 >> 9], 1);
    atomicAdd(&h[c3 >> 9], 1);
  }
  for (; i < s1; i += 256) atomicAdd(&h[ecol[i] >> 9], 1);
  __syncthreads();
  for (int b = threadIdx.x; b < nb; b += 256) cntmat[g * nb + b] = h[b];
}

// ---- per-bucket column scan over g; column total -> colsum[b] ----
__global__ __launch_bounds__(256) void k_colscan(int* __restrict__ cntmat,
                                                 int* __restrict__ colsum,
                                                 int G, int nb) {
  __shared__ int wsum[4];
  __shared__ int carry_s;
  int b = blockIdx.x;
  if (threadIdx.x == 0) carry_s = 0;
  __syncthreads();
  for (int base = 0; base < G; base += 256) {
    int i = base + threadIdx.x;
    int v = (i < G) ? cntmat[i * nb + b] : 0;
    int ex = blockScanExclusive256(v, wsum);
    int c = carry_s;
    __syncthreads();
    if (i < G) cntmat[i * nb + b] = ex + c;
    if (threadIdx.x == 255) carry_s = c + ex + v;
    __syncthreads();
  }
  if (threadIdx.x == 0) colsum[b] = carry_s;
}

// ---- bucket exclusive scan (1 block) ----
__global__ __launch_bounds__(256) void k_bscan(const int* __restrict__ colsum,
                                               int* __restrict__ bbase,
                                               int nb, int etot) {
  __shared__ int wsum[4];
  __shared__ int carry_s;
  if (threadIdx.x == 0) carry_s = 0;
  __syncthreads();
  for (int base = 0; base < nb; base += 256) {
    int i = base + threadIdx.x;
    int v = (i < nb) ? colsum[i] : 0;
    int ex = blockScanExclusive256(v, wsum);
    int c = carry_s;
    __syncthreads();
    if (i < nb) bbase[i] = ex + c;
    if (threadIdx.x == 255) carry_s = c + ex + v;
    __syncthreads();
  }
  if (threadIdx.x == 0) bbase[nb] = etot;
}

// ---- heterogeneous-role: scatter blocks [0,gs), transform blocks [gs,..) ----
__global__ __launch_bounds__(256) void k_scat_xf(
    const int* __restrict__ erow, const int* __restrict__ ecol,
    const int* __restrict__ cntmat, const int* __restrict__ bbase,
    unsigned* __restrict__ sorted, int e, int chunk, int nb, int gs,
    const float* __restrict__ x, const float* __restrict__ W,
    __half* __restrict__ t1raw, int n) {
  if ((int)blockIdx.x < gs) {
    // ---------------- scatter role ----------------
    __shared__ int base[256];
    int g = blockIdx.x;
    for (int b = threadIdx.x; b < nb; b += 256)
      base[b] = bbase[b] + cntmat[g * nb + b];  // contiguous 784B read
    __syncthreads();
    int s0 = g * chunk;
    int s1 = min(e, s0 + chunk);
    int i = s0 + threadIdx.x;
    for (; i + 768 < s1; i += 1024) {
      int c0 = ecol[i],       c1 = ecol[i + 256], c2 = ecol[i + 512], c3 = ecol[i + 768];
      int r0 = erow[i],       r1 = erow[i + 256], r2 = erow[i + 512], r3 = erow[i + 768];
      int p0 = atomicAdd(&base[c0 >> 9], 1);
      int p1 = atomicAdd(&base[c1 >> 9], 1);
      int p2 = atomicAdd(&base[c2 >> 9], 1);
      int p3 = atomicAdd(&base[c3 >> 9], 1);
      sorted[p0] = ((unsigned)r0 << 9) | (unsigned)(c0 & 511);
      sorted[p1] = ((unsigned)r1 << 9) | (unsigned)(c1 & 511);
      sorted[p2] = ((unsigned)r2 << 9) | (unsigned)(c2 & 511);
      sorted[p3] = ((unsigned)r3 << 9) | (unsigned)(c3 & 511);
    }
    for (; i < s1; i += 256) {
      int c = ecol[i];
      int p = atomicAdd(&base[c >> 9], 1);
      sorted[p] = ((unsigned)erow[i] << 9) | (unsigned)(c & 511);
    }
    return;
  }

  // ---------------- transform role: wave per row, W (512x16) in regs ----------------
  int L = threadIdx.x & 63;
  int wid = (blockIdx.x - gs) * 4 + (threadIdx.x >> 6);
  int nw = (gridDim.x - gs) * 4;

  float w[8][16];
  const float4* W4 = reinterpret_cast<const float4*>(W);
#pragma unroll
  for (int i = 0; i < 4; ++i) {
#pragma unroll
    for (int c4 = 0; c4 < 4; ++c4) {
      float4 va = W4[(4 * L + i) * 4 + c4];
      w[i][c4 * 4 + 0] = va.x; w[i][c4 * 4 + 1] = va.y;
      w[i][c4 * 4 + 2] = va.z; w[i][c4 * 4 + 3] = va.w;
      float4 vb = W4[(256 + 4 * L + i) * 4 + c4];
      w[4 + i][c4 * 4 + 0] = vb.x; w[4 + i][c4 * 4 + 1] = vb.y;
      w[4 + i][c4 * 4 + 2] = vb.z; w[4 + i][c4 * 4 + 3] = vb.w;
    }
  }
  int col = ((L & 1) << 3) | ((L & 2) << 1) | ((L & 4) >> 1) | ((L & 8) >> 3);

  for (int r = wid; r < n; r += nw) {
    const float4* xr = reinterpret_cast<const float4*>(x + (size_t)r * 512);
    float4 v0 = xr[L];
    float4 v1 = xr[64 + L];
    float acc[16];
#pragma unroll
    for (int c = 0; c < 16; ++c) {
      float a = v0.x * w[0][c];
      a = fmaf(v0.y, w[1][c], a);
      a = fmaf(v0.z, w[2][c], a);
      a = fmaf(v0.w, w[3][c], a);
      a = fmaf(v1.x, w[4][c], a);
      a = fmaf(v1.y, w[5][c], a);
      a = fmaf(v1.z, w[6][c], a);
      a = fmaf(v1.w, w[7][c], a);
      acc[c] = a;
    }
#pragma unroll
    for (int j = 0; j < 8; ++j) {
      float send = (L & 1) ? acc[j] : acc[j + 8];
      float recv = __shfl_xor(send, 1, 64);
      acc[j] = ((L & 1) ? acc[j + 8] : acc[j]) + recv;
    }
#pragma unroll
    for (int j = 0; j < 4; ++j) {
      float send = (L & 2) ? acc[j] : acc[j + 4];
      float recv = __shfl_xor(send, 2, 64);
      acc[j] = ((L & 2) ? acc[j + 4] : acc[j]) + recv;
    }
#pragma unroll
    for (int j = 0; j < 2; ++j) {
      float send = (L & 4) ? acc[j] : acc[j + 2];
      float recv = __shfl_xor(send, 4, 64);
      acc[j] = ((L & 4) ? acc[j + 2] : acc[j]) + recv;
    }
    {
      float send = (L & 8) ? acc[0] : acc[1];
      float recv = __shfl_xor(send, 8, 64);
      acc[0] = ((L & 8) ? acc[1] : acc[0]) + recv;
    }
    float s = acc[0];
    s += __shfl_xor(s, 16, 64);
    s += __shfl_xor(s, 32, 64);
    if (L < 16) t1raw[r * 16 + col] = __float2half(s);
  }
}

// ---- pass2: per-bucket hist + scan + rowptr/dis + t1 scale + csr fill ----
__global__ __launch_bounds__(512) void k_pass2(const unsigned* __restrict__ sorted,
                                               const int* __restrict__ bbase,
                                               float* __restrict__ dis,
                                               int* __restrict__ rowptr,
                                               __half* __restrict__ t1,
                                               int* __restrict__ csr,
                                               int n, int etot) {
  __shared__ int hist[512];
  __shared__ int cur[512];
  __shared__ int wsum[8];
  int b = blockIdx.x;
  hist[threadIdx.x] = 0;
  __syncthreads();
  int s0 = bbase[b], s1 = bbase[b + 1];
  for (int i = s0 + threadIdx.x; i < s1; i += 512)
    atomicAdd(&hist[sorted[i] & 511], 1);
  __syncthreads();
  int j = threadIdx.x;
  int node = (b << 9) + j;
  int deg = hist[j];
  int ex = blockScanExclusive512(deg, wsum);
  float dv = rsqrtf((float)(deg + 1));  // +1 self loop
  cur[j] = s0 + ex;
  if (node < n) {
    dis[node] = dv;
    rowptr[node] = s0 + ex;
    // scale this node's t1 row in place (bucket rows contiguous, streaming)
    __half2* t2 = reinterpret_cast<__half2*>(t1 + ((size_t)node << 4));
#pragma unroll
    for (int q = 0; q < 8; ++q) {
      float2 fv = __half22float2(t2[q]);
      fv.x *= dv; fv.y *= dv;
      t2[q] = __float22half2_rn(fv);
    }
  }
  if (b == 0 && threadIdx.x == 0) rowptr[n] = etot;
  __syncthreads();
  for (int i = s0 + threadIdx.x; i < s1; i += 512) {
    unsigned v = sorted[i];
    int pos = atomicAdd(&cur[v & 511], 1);
    csr[pos] = (int)(v >> 9);
  }
}

// ---- common gather: acc = self + sum of neighbor rows (fp16 rows, fp32
//      accumulate). 16-edge unroll, 4 independent accumulators: ~16
//      independent 32B row-loads in flight per wave iteration. ----
__device__ __forceinline__ float gather16(const __half* __restrict__ hs,
                                          const int* __restrict__ rowptr,
                                          const int* __restrict__ csr,
                                          int node, int f) {
  float acc0 = __half2float(hs[(node << 4) + f]);  // self loop (pre-scaled)
  int e0 = rowptr[node], e1 = rowptr[node + 1];
  int e = e0;
  float acc1 = 0.f, acc2 = 0.f, acc3 = 0.f;
  for (; e + 16 <= e1; e += 16) {
    int r0  = csr[e + 0],  r1  = csr[e + 1],  r2  = csr[e + 2],  r3  = csr[e + 3];
    int r4  = csr[e + 4],  r5  = csr[e + 5],  r6  = csr[e + 6],  r7  = csr[e + 7];
    int r8  = csr[e + 8],  r9  = csr[e + 9],  r10 = csr[e + 10], r11 = csr[e + 11];
    int r12 = csr[e + 12], r13 = csr[e + 13], r14 = csr[e + 14], r15 = csr[e + 15];
    __half v0  = hs[(r0  << 4) + f], v1  = hs[(r1  << 4) + f];
    __half v2  = hs[(r2  << 4) + f], v3  = hs[(r3  << 4) + f];
    __half v4  = hs[(r4  << 4) + f], v5  = hs[(r5  << 4) + f];
    __half v6  = hs[(r6  << 4) + f], v7  = hs[(r7  << 4) + f];
    __half v8  = hs[(r8  << 4) + f], v9  = hs[(r9  << 4) + f];
    __half v10 = hs[(r10 << 4) + f], v11 = hs[(r11 << 4) + f];
    __half v12 = hs[(r12 << 4) + f], v13 = hs[(r13 << 4) + f];
    __half v14 = hs[(r14 << 4) + f], v15 = hs[(r15 << 4) + f];
    acc0 += (__half2float(v0)  + __half2float(v1))  + (__half2float(v2)  + __half2float(v3));
    acc1 += (__half2float(v4)  + __half2float(v5))  + (__half2float(v6)  + __half2float(v7));
    acc2 += (__half2float(v8)  + __half2float(v9))  + (__half2float(v10) + __half2float(v11));
    acc3 += (__half2float(v12) + __half2float(v13)) + (__half2float(v14) + __half2float(v15));
  }
  for (; e + 4 <= e1; e += 4) {
    int r0 = csr[e + 0], r1 = csr[e + 1], r2 = csr[e + 2], r3 = csr[e + 3];
    float v0 = __half2float(hs[(r0 << 4) + f]), v1 = __half2float(hs[(r1 << 4) + f]);
    float v2 = __half2float(hs[(r2 << 4) + f]), v3 = __half2float(hs[(r3 << 4) + f]);
    acc0 += (v0 + v1) + (v2 + v3);
  }
  for (; e < e1; ++e) acc0 += __half2float(hs[(csr[e] << 4) + f]);
  return (acc0 + acc1) + (acc2 + acc3);
}

// out = relu(dis*acc + b) * dis   (layer-1 agg, prescaled for next gather)
__global__ __launch_bounds__(256) void k_agg_rb(
    const __half* __restrict__ hs, const int* __restrict__ rowptr,
    const int* __restrict__ csr, const float* __restrict__ dis,
    const float* __restrict__ b, __half* __restrict__ out, int n) {
  int node = blockIdx.x * 16 + threadIdx.x / 16;
  int f = threadIdx.x % 16;
  if (node >= n) return;
  float acc = gather16(hs, rowptr, csr, node, f);
  float d = dis[node];
  float t = fmaxf(fmaf(d, acc, b[f]), 0.f);
  out[(node << 4) + f] = __float2half(t * d);
}

// mid: t3 = (relu((dis*acc)@W2 + b2) @ W3) * dis   -- 16->32->16 in-register
__global__ __launch_bounds__(256) void k_agg_mid(
    const __half* __restrict__ hs, const int* __restrict__ rowptr,
    const int* __restrict__ csr, const float* __restrict__ dis,
    const float* __restrict__ W2, const float* __restrict__ b2,
    const float* __restrict__ W3, __half* __restrict__ out, int n) {
  __shared__ float w2s[512];  // [16][32]
  __shared__ float w3s[512];  // [32][16]
  __shared__ float b2s[32];
  for (int i = threadIdx.x; i < 512; i += 256) { w2s[i] = W2[i]; w3s[i] = W3[i]; }
  if (threadIdx.x < 32) b2s[threadIdx.x] = b2[threadIdx.x];
  __syncthreads();
  int node = blockIdx.x * 16 + threadIdx.x / 16;
  int f = threadIdx.x % 16;
  if (node >= n) return;
  float acc = gather16(hs, rowptr, csr, node, f);
  float d = dis[node];
  float v = d * acc;  // g2[f]
  int base = threadIdx.x & 48;  // 16-group base lane in wave
  float a0 = b2s[f], a1 = b2s[f + 16];
#pragma unroll
  for (int k = 0; k < 16; ++k) {
    float vk = __shfl(v, base + k, 64);
    a0 = fmaf(vk, w2s[k * 32 + f], a0);
    a1 = fmaf(vk, w2s[k * 32 + 16 + f], a1);
  }
  a0 = fmaxf(a0, 0.f);
  a1 = fmaxf(a1, 0.f);
  float t = 0.f;
#pragma unroll
  for (int c = 0; c < 16; ++c) {
    float h0 = __shfl(a0, base + c, 64);
    float h1 = __shfl(a1, base + c, 64);
    t = fmaf(h0, w3s[c * 16 + f], t);
    t = fmaf(h1, w3s[(c + 16) * 16 + f], t);
  }
  out[(node << 4) + f] = __float2half(t * d);
}

// final: h = relu(dis*acc + b3) -> outh;  out = h@Wc + bc -> outc
__global__ __launch_bounds__(256) void k_agg_out(
    const __half* __restrict__ hs, const int* __restrict__ rowptr,
    const int* __restrict__ csr, const float* __restrict__ dis,
    const float* __restrict__ b3, const float* __restrict__ Wc,
    const float* __restrict__ bc, float* __restrict__ outh,
    float* __restrict__ outc, int n) {
  __shared__ float wcs[256];  // [16][16]
  __shared__ float b3s[16];
  __shared__ float bcs[16];
  if (threadIdx.x < 256) wcs[threadIdx.x] = Wc[threadIdx.x];
  if (threadIdx.x < 16) { b3s[threadIdx.x] = b3[threadIdx.x]; bcs[threadIdx.x] = bc[threadIdx.x]; }
  __syncthreads();
  int node = blockIdx.x * 16 + threadIdx.x / 16;
  int f = threadIdx.x % 16;
  if (node >= n) return;
  float acc = gather16(hs, rowptr, csr, node, f);
  float d = dis[node];
  float h = fmaxf(fmaf(d, acc, b3s[f]), 0.f);
  outh[(node << 4) + f] = h;
  int base = threadIdx.x & 48;
  float o = bcs[f];
#pragma unroll
  for (int k = 0; k < 16; ++k) {
    float hk = __shfl(h, base + k, 64);
    o = fmaf(hk, wcs[k * 16 + f], o);
  }
  outc[(node << 4) + f] = o;
}

extern "C" void kernel_launch(void* const* d_in, const int* in_sizes, int n_in,
                              void* d_out, int out_size, void* d_ws, size_t ws_size,
                              hipStream_t stream) {
  (void)n_in; (void)out_size;
  const float* x  = (const float*)d_in[0];
  const int*   ei = (const int*)d_in[1];
  const float* W1 = (const float*)d_in[2];
  const float* b1 = (const float*)d_in[3];
  const float* W2 = (const float*)d_in[4];
  const float* b2 = (const float*)d_in[5];
  const float* W3 = (const float*)d_in[6];
  const float* b3 = (const float*)d_in[7];
  const float* Wc = (const float*)d_in[8];
  const float* bc = (const float*)d_in[9];

  const int F = 512;
  int N = in_sizes[0] / F;
  int E = in_sizes[1] / 2;
  const int* erow = ei;        // sources
  const int* ecol = ei + E;    // targets
  int NB = (N + 511) >> 9;     // buckets of 512 nodes (N<=131072)
  const int GS = 512;          // scatter grid: chunk=E/512 -> 256B write runs
  const int GT = 1536;         // transform-role blocks
  int chunk = (E + GS - 1) / GS;

  auto align = [](size_t v) { return (v + 255) & ~(size_t)255; };
  char* p = (char*)d_ws;
  int*   cntmat = (int*)p;   p += align((size_t)GS * NB * 4);
  int*   colsum = (int*)p;   p += align(256 * 4);
  int*   bbase  = (int*)p;   p += align(257 * 4);
  float* dis    = (float*)p; p += align((size_t)N * 4);
  int*   rowptr = (int*)p;   p += align(((size_t)N + 1) * 4);
  int*   csr    = (int*)p;   p += align((size_t)E * 4);
  unsigned* sorted = (unsigned*)p; p += align((size_t)E * 4);
  // bufA does not alias sorted (sorted is live while t1 is written)
  __half* bufA = (__half*)p; p += align((size_t)N * 16 * 2);
  __half* bufB = (__half*)p; p += align((size_t)N * 16 * 2);
  if ((size_t)(p - (char*)d_ws) > ws_size) return;  // fail visibly

  float* outc = (float*)d_out;                   // [N,16] classifier out
  float* outh = (float*)d_out + (size_t)N * 16;  // [N,16] h

  // ---- CSR build + fused layer-1 transform ----
  k_bhist<<<GS, 256, 0, stream>>>(ecol, cntmat, E, chunk, NB);
  k_colscan<<<NB, 256, 0, stream>>>(cntmat, colsum, GS, NB);
  k_bscan<<<1, 256, 0, stream>>>(colsum, bbase, NB, E);
  // heterogeneous roles: 512 scatter blocks + 1536 transform blocks
  k_scat_xf<<<GS + GT, 256, 0, stream>>>(erow, ecol, cntmat, bbase, sorted, E,
                                         chunk, NB, GS, x, W1, bufA, N);
  // hist+scan+rowptr+dis, t1 *= dis, csr fill
  k_pass2<<<NB, 512, 0, stream>>>(sorted, bbase, dis, rowptr, bufA, csr, N, E);

  // ---- layers ----
  // hs1 = relu(dis*agg(t1)+b1)*dis  (fp16)
  k_agg_rb<<<(N + 15) / 16, 256, 0, stream>>>(bufA, rowptr, csr, dis, b1, bufB, N);
  // t3 = (relu((dis*agg(hs1))@W2+b2)@W3)*dis  (fp16)
  k_agg_mid<<<(N + 15) / 16, 256, 0, stream>>>(bufB, rowptr, csr, dis, W2, b2, W3, bufA, N);
  // h = relu(dis*agg(t3)+b3) -> outh;  out = h@Wc+bc -> outc  (fp32 outputs)
  k_agg_out<<<(N + 15) / 16, 256, 0, stream>>>(bufA, rowptr, csr, dis, b3, Wc, bc, outh, outc, N);
}